// Round 13
// baseline (479.207 us; speedup 1.0000x reference)
//
#include <hip/hip_runtime.h>
#include <hip/hip_bf16.h>

// Problem constants
static constexpr int kB      = 4;
static constexpr int kT      = 1024;
static constexpr int kDIN    = 8;
static constexpr int kDMODEL = 512;
static constexpr int kHOR    = 24;
static constexpr int kDOUT   = 8;
static constexpr int kDSTATE = 64;
static constexpr int kDINNER = 1024;
static constexpr int kDTRANK = 32;
static constexpr int kXPROJ  = 160;          // 32 + 64 + 64
static constexpr int kXPAD   = 256;          // padded xdb_bf row stride
static constexpr int kBT     = kB * kT;      // 4096
static constexpr int kNLAYER = 2;

typedef __bf16 bf16x8 __attribute__((ext_vector_type(8)));
typedef float  f32x4  __attribute__((ext_vector_type(4)));

__device__ __forceinline__ float silu_f(float x)     { return x / (1.f + __expf(-x)); }
__device__ __forceinline__ float softplus_f(float x) { return (x > 20.f) ? x : log1pf(__expf(x)); }
__device__ __forceinline__ float gelu_f(float x)     { return 0.5f * x * (1.f + erff(x * 0.70710678118654752f)); }

// async global->LDS 16B
__device__ __forceinline__ void gld_lds16(const void* g, void* l) {
    __builtin_amdgcn_global_load_lds(
        (const __attribute__((address_space(1))) unsigned int*)g,
        (__attribute__((address_space(3))) unsigned int*)l, 16, 0, 0);
}

template<int CTRL>
__device__ __forceinline__ float dpp_mov(float v) {
    return __int_as_float(__builtin_amdgcn_update_dpp(
        0, __float_as_int(v), CTRL, 0xf, 0xf, false));
}

// ---------------------------------------------------------------------------
// ALL weight transposes in ONE dispatch (region-decoded flat grid).
// out[n][k] = bf16(in[k][n]); OOB reads -> 0 (zero-pads dt's K 32->64).
// Regions: xz [0,2048)  xp [2048,2368)  dt [2368,2496)  wout [2496,3520)
// ---------------------------------------------------------------------------
__global__ __launch_bounds__(256) void wtrans_all_kernel(
    const float* __restrict__ Wxz, const float* __restrict__ Wxp,
    const float* __restrict__ Wdt, const float* __restrict__ Wout,
    __hip_bfloat16* __restrict__ oxz, __hip_bfloat16* __restrict__ oxp,
    __hip_bfloat16* __restrict__ odt, __hip_bfloat16* __restrict__ oout)
{
    __shared__ float tile[32][33];
    const int bid = blockIdx.x;
    const int tid = threadIdx.x;

    const float* in; __hip_bfloat16* out;
    int K, N, Kpad, TX, loc;
    if (bid < 2048) {               // W_xz: (512,2048) -> (2048,512), 64x16 tiles
        int l = bid >> 10; loc = bid & 1023;
        in = Wxz + (size_t)l * 512 * 2048; out = oxz + (size_t)l * 2048 * 512;
        K = 512; N = 2048; Kpad = 512; TX = 64;
    } else if (bid < 2368) {        // W_xp: (1024,160) -> (256pad,1024), 5x32 tiles
        int r = bid - 2048; int l = r / 160; loc = r % 160;
        in = Wxp + (size_t)l * 1024 * 160; out = oxp + (size_t)l * 256 * 1024;
        K = 1024; N = 160; Kpad = 1024; TX = 5;
    } else if (bid < 2496) {        // W_dt: (32,1024) -> (1024,64pad), 32x2 tiles
        int r = bid - 2368; int l = r >> 6; loc = r & 63;
        in = Wdt + (size_t)l * 32 * 1024; out = odt + (size_t)l * 1024 * 64;
        K = 32; N = 1024; Kpad = 64; TX = 32;
    } else {                        // W_out: (1024,512) -> (512,1024), 16x32 tiles
        int r = bid - 2496; int l = r >> 9; loc = r & 511;
        in = Wout + (size_t)l * 1024 * 512; out = oout + (size_t)l * 512 * 1024;
        K = 1024; N = 512; Kpad = 1024; TX = 16;
    }
    const int n0 = (loc % TX) * 32;
    const int k0 = (loc / TX) * 32;

#pragma unroll
    for (int p = 0; p < 4; ++p) {
        int idx = p * 256 + tid;
        int ki = idx >> 5, ni = idx & 31;
        float v = 0.f;
        if (k0 + ki < K && n0 + ni < N) v = in[(size_t)(k0 + ki) * N + n0 + ni];
        tile[ki][ni] = v;
    }
    __syncthreads();
#pragma unroll
    for (int p = 0; p < 4; ++p) {
        int idx = p * 256 + tid;
        int ni = idx >> 5, ki = idx & 31;
        if (n0 + ni < N)
            out[(size_t)(n0 + ni) * Kpad + k0 + ki] = __float2bfloat16(tile[ki][ni]);
    }
}

// ---------------------------------------------------------------------------
// Fold layer-0 input projection into xz:  wf[n][r] (r=0..7) = (W_in @ W_xz0)
// transposed per-column; wf[n][8] = b_in @ W_xz0 column n. Layout [2048][12].
// ---------------------------------------------------------------------------
__global__ __launch_bounds__(256) void wfold_kernel(
    const float* __restrict__ Win, const float* __restrict__ bin,
    const float* __restrict__ Wxz0, float* __restrict__ wf)
{
    __shared__ float sred[3][64][9];
    const int t    = threadIdx.x & 63;
    const int part = threadIdx.x >> 6;
    const int col  = blockIdx.x * 64 + t;

    float acc[9];
#pragma unroll
    for (int r = 0; r < 9; ++r) acc[r] = 0.f;

    const int k0 = part * 128;
#pragma unroll 4
    for (int k = k0; k < k0 + 128; ++k) {
        float wv = Wxz0[(size_t)k * 2048 + col];
#pragma unroll
        for (int r = 0; r < 8; ++r)
            acc[r] = fmaf(Win[r * kDMODEL + k], wv, acc[r]);
        acc[8] = fmaf(bin[k], wv, acc[8]);
    }
    if (part > 0) {
#pragma unroll
        for (int r = 0; r < 9; ++r) sred[part - 1][t][r] = acc[r];
    }
    __syncthreads();
    if (part == 0) {
#pragma unroll
        for (int r = 0; r < 9; ++r)
            wf[(size_t)col * 12 + r] =
                acc[r] + sred[0][t][r] + sred[1][t][r] + sred[2][t][r];
    }
}

// ---------------------------------------------------------------------------
// Layer-0 fused xz + conv + SiLU (K=8 folded weight).
// blockIdx = m*2 + half. half 0: xc = silu(conv(xb taps computed on the fly));
// half 1: z = silu(dot). 4 cols/thread.
// ---------------------------------------------------------------------------
__global__ __launch_bounds__(256) void xz0_conv_kernel(
    const float* __restrict__ x, const float* __restrict__ wf,
    const float* __restrict__ cw, const float* __restrict__ cb,
    __hip_bfloat16* __restrict__ xcv, __hip_bfloat16* __restrict__ z)
{
    const int bid  = blockIdx.x;
    const int m    = bid >> 1;
    const int half = bid & 1;
    const int t    = m & (kT - 1);
    const int n4   = threadIdx.x * 4 + half * kDINNER;

    // folded weights for 4 cols (9 each)
    float wreg[4][9];
#pragma unroll
    for (int c = 0; c < 4; ++c) {
        const float* wc = wf + (size_t)(n4 + c) * 12;
#pragma unroll
        for (int r = 0; r < 9; ++r) wreg[c][r] = wc[r];
    }

    if (half == 1) {
        const float* xr = x + (size_t)m * kDIN;
        float xv[8];
#pragma unroll
        for (int r = 0; r < 8; ++r) xv[r] = xr[r];
        __bf16 o4[4];
#pragma unroll
        for (int c = 0; c < 4; ++c) {
            float a = wreg[c][8];
#pragma unroll
            for (int r = 0; r < 8; ++r) a = fmaf(xv[r], wreg[c][r], a);
            o4[c] = (__bf16)silu_f(a);
        }
        *reinterpret_cast<ushort4*>(z + (size_t)m * kDINNER + (n4 - kDINNER)) =
            *reinterpret_cast<ushort4*>(o4);
    } else {
        float acc[4];
        float4 cwv[4];
#pragma unroll
        for (int c = 0; c < 4; ++c) {
            acc[c] = cb[n4 + c];
            cwv[c] = *reinterpret_cast<const float4*>(cw + (n4 + c) * 4);
        }
#pragma unroll
        for (int sh = 0; sh < 4; ++sh) {
            if (t >= sh) {
                const float* xr = x + (size_t)(m - sh) * kDIN;
                float xv[8];
#pragma unroll
                for (int r = 0; r < 8; ++r) xv[r] = xr[r];
#pragma unroll
                for (int c = 0; c < 4; ++c) {
                    float a = wreg[c][8];
#pragma unroll
                    for (int r = 0; r < 8; ++r) a = fmaf(xv[r], wreg[c][r], a);
                    float wk = (sh == 0) ? cwv[c].w : (sh == 1) ? cwv[c].z
                             : (sh == 2) ? cwv[c].y : cwv[c].x;
                    acc[c] = fmaf(a, wk, acc[c]);
                }
            }
        }
        __bf16 o4[4];
#pragma unroll
        for (int c = 0; c < 4; ++c) o4[c] = (__bf16)silu_f(acc[c]);
        *reinterpret_cast<ushort4*>(xcv + (size_t)m * kDINNER + n4) =
            *reinterpret_cast<ushort4*>(o4);
    }
}

// ---------------------------------------------------------------------------
// MFMA bf16 GEMM, B-transposed. BM in {128,64}, BN in {128,64}, BK=64, 4 waves.
// MODE 0: f32 C only
// MODE 1: plain f32 C + bf16 C2
// MODE 2: dt: softplus(v + bias[col]) -> f32 C (coalesced)
// MODE 4: XZ split, both bf16 (col<1024 -> bf16 xb ; col>=1024 -> silu -> z)
// MODE 5: xproj split: col<32 -> bf16 C2 (stride kXPAD);
//         col 32..96  -> B: C[(row>>1)*256 + (col-32)*4 + (row&1)*2]
//         col 96..160 -> C: C[(row>>1)*256 + (col-96)*4 + (row&1)*2 + 1]
// MODE 6: bf16 C2 only (stride ldc)
// ---------------------------------------------------------------------------
template<int MODE, int BM, int BN>
__global__ __launch_bounds__(256) void mfma_gemm_bt(
    const __hip_bfloat16* __restrict__ A, int lda,
    const __hip_bfloat16* __restrict__ BT, int ldb,
    const float* __restrict__ bias,
    float* __restrict__ C, int ldc,
    void* __restrict__ C2,
    int K)
{
    constexpr int WN  = (BM == 128 && BN == 64) ? 1 : 2;
    constexpr int WM  = 4 / WN;
    constexpr int WTM = BM / WM;
    constexpr int WTN = BN / WN;
    constexpr int MI  = WTM / 16;
    constexpr int NJ  = WTN / 16;

    __shared__ __align__(16) __hip_bfloat16 sA[BM][64];
    __shared__ __align__(16) __hip_bfloat16 sB[BN][64];

    const int tid  = threadIdx.x;
    const int lane = tid & 63;
    const int w    = tid >> 6;
    const int m0   = blockIdx.y * BM;
    const int n0   = blockIdx.x * BN;
    const int wm   = (WN == 1) ? w : (w >> 1);
    const int wn   = (WN == 1) ? 0 : (w & 1);

    f32x4 acc[MI][NJ] = {};

    const int lrow = lane & 15;
    const int lk   = (lane >> 4) << 3;

    const int grow = tid >> 3;
    const int gcol = (tid & 7) * 8;
    char* ldsA = (char*)&sA[0][0] + w * 1024;
    char* ldsB = (char*)&sB[0][0] + w * 1024;

    for (int k0 = 0; k0 < K; k0 += 64) {
        __syncthreads();
#pragma unroll
        for (int p = 0; p < BM / 32; ++p)
            gld_lds16(A + (size_t)(m0 + grow + p * 32) * lda + k0 + gcol, ldsA + p * 4096);
#pragma unroll
        for (int p = 0; p < BN / 32; ++p)
            gld_lds16(BT + (size_t)(n0 + grow + p * 32) * ldb + k0 + gcol, ldsB + p * 4096);
        __syncthreads();
#pragma unroll
        for (int ks = 0; ks < 2; ++ks) {
            bf16x8 af[MI], bfr[NJ];
#pragma unroll
            for (int i = 0; i < MI; ++i)
                af[i] = *reinterpret_cast<const bf16x8*>(&sA[wm * WTM + i * 16 + lrow][ks * 32 + lk]);
#pragma unroll
            for (int j = 0; j < NJ; ++j)
                bfr[j] = *reinterpret_cast<const bf16x8*>(&sB[wn * WTN + j * 16 + lrow][ks * 32 + lk]);
#pragma unroll
            for (int i = 0; i < MI; ++i)
#pragma unroll
                for (int j = 0; j < NJ; ++j)
                    acc[i][j] = __builtin_amdgcn_mfma_f32_16x16x32_bf16(af[i], bfr[j], acc[i][j], 0, 0, 0);
        }
    }

    const int crow = (lane >> 4) * 4;
    const int ccol = lane & 15;
#pragma unroll
    for (int i = 0; i < MI; ++i) {
#pragma unroll
        for (int j = 0; j < NJ; ++j) {
#pragma unroll
            for (int r = 0; r < 4; ++r) {
                int row = m0 + wm * WTM + i * 16 + crow + r;
                int col = n0 + wn * WTN + j * 16 + ccol;
                float v = acc[i][j][r];
                if (MODE == 0) {
                    C[(size_t)row * ldc + col] = v;
                } else if (MODE == 1) {
                    C[(size_t)row * ldc + col] = v;
                    ((__hip_bfloat16*)C2)[(size_t)row * ldc + col] = __float2bfloat16(v);
                } else if (MODE == 2) {
                    C[(size_t)row * ldc + col] = softplus_f(v + bias[col]);
                } else if (MODE == 4) {
                    if (col < kDINNER)
                        ((__hip_bfloat16*)C)[(size_t)row * ldc + col] = __float2bfloat16(v);
                    else
                        ((__hip_bfloat16*)C2)[(size_t)row * ldc + (col - kDINNER)] =
                            __float2bfloat16(silu_f(v));
                } else if (MODE == 5) {
                    if (col < kDTRANK)
                        ((__hip_bfloat16*)C2)[(size_t)row * kXPAD + col] = __float2bfloat16(v);
                    else if (col < kDTRANK + kDSTATE)
                        C[(size_t)(row >> 1) * 256 + (col - kDTRANK) * 4 + (row & 1) * 2] = v;
                    else if (col < kXPROJ)
                        C[(size_t)(row >> 1) * 256 + (col - kDTRANK - kDSTATE) * 4 + (row & 1) * 2 + 1] = v;
                } else {  // MODE 6: bf16 only
                    ((__hip_bfloat16*)C2)[(size_t)row * ldc + col] = __float2bfloat16(v);
                }
            }
        }
    }
}

// ---------------------------------------------------------------------------
// Depthwise causal conv (width 4) + bias + SiLU. 8 channels/thread. (layer 1)
// ---------------------------------------------------------------------------
__global__ __launch_bounds__(256) void conv_silu_kernel(
    const __hip_bfloat16* __restrict__ xb,
    const float* __restrict__ cw, const float* __restrict__ cb,
    __hip_bfloat16* __restrict__ xc)
{
    int idx = blockIdx.x * 256 + threadIdx.x;      // over BT*128
    int dg  = (idx & 127) * 8;
    int bt  = idx >> 7;
    int t   = bt & (kT - 1);

    float4 wv[8];
#pragma unroll
    for (int k = 0; k < 8; ++k)
        wv[k] = *reinterpret_cast<const float4*>(cw + (dg + k) * 4);

    float acc[8];
#pragma unroll
    for (int k = 0; k < 8; ++k) acc[k] = cb[dg + k];

    const __hip_bfloat16* base = xb + (size_t)bt * kDINNER + dg;
    {
        bf16x8 v = *reinterpret_cast<const bf16x8*>(base);
#pragma unroll
        for (int k = 0; k < 8; ++k) acc[k] = fmaf((float)v[k], wv[k].w, acc[k]);
    }
    if (t >= 1) {
        bf16x8 v = *reinterpret_cast<const bf16x8*>(base - kDINNER);
#pragma unroll
        for (int k = 0; k < 8; ++k) acc[k] = fmaf((float)v[k], wv[k].z, acc[k]);
    }
    if (t >= 2) {
        bf16x8 v = *reinterpret_cast<const bf16x8*>(base - 2 * kDINNER);
#pragma unroll
        for (int k = 0; k < 8; ++k) acc[k] = fmaf((float)v[k], wv[k].y, acc[k]);
    }
    if (t >= 3) {
        bf16x8 v = *reinterpret_cast<const bf16x8*>(base - 3 * kDINNER);
#pragma unroll
        for (int k = 0; k < 8; ++k) acc[k] = fmaf((float)v[k], wv[k].x, acc[k]);
    }
    bf16x8 o;
#pragma unroll
    for (int k = 0; k < 8; ++k) o[k] = (__bf16)silu_f(acc[k]);
    *reinterpret_cast<bf16x8*>(xc + (size_t)bt * kDINNER + dg) = o;
}

// ---------------------------------------------------------------------------
// Selective scan. Block = 4 waves (channels d0..d0+3, same b); lane = state n.
// XCD remap: batch b owns an XCD pair -> its panels stay L2-resident.
// Chunk of 32 steps split into two 16-step halves: tree16(half A) is
// independent of recurrence(half B) -> scheduler fills the serial s-chain
// and bpermute-latency stalls with tree work. Register footprint unchanged
// vs the proven 52-VGPR version (same 32 yv floats).
// ---------------------------------------------------------------------------
__global__ __launch_bounds__(256, 4) void scan_kernel(
    const float* __restrict__ dt,            // (bt,1024) f32
    const float* __restrict__ xdbi,          // (bt/2, 64, 4): B0,C0,B1,C1
    const __hip_bfloat16* __restrict__ xc,   // (bt,1024)
    const __hip_bfloat16* __restrict__ zs,   // (bt,1024) silu(z)
    const float* __restrict__ Alog,          // (1024,64)
    const float* __restrict__ Dsk,           // (1024,)
    __hip_bfloat16* __restrict__ yg)         // (bt,1024)
{
    __shared__ __align__(16) float sBC[2][16][64][4];  // 32 KB
    __shared__ __align__(16) float sDT[2][16][4][4];   // 2 KB

    const int tid  = threadIdx.x;
    const int lane = tid & 63;
    const int w    = tid >> 6;
    const int bb = blockIdx.x;
    const int b  = (bb & 7) >> 1;
    const int d0 = ((bb >> 3) + (bb & 1) * 128) * 4;
    const int d  = d0 + w;

    const float a2  = -__expf(Alog[d * kDSTATE + lane]) * 1.44269504f;
    const float dsk = Dsk[d];
    const size_t rowbase  = (size_t)b * kT;
    const size_t pairbase = (size_t)b * (kT / 2);
    float s = 0.f;

    auto stageBC = [&](int c, int buf) {
        const float* src = xdbi + (pairbase + c * 16 + 4 * w) * 256 + lane * 4;
#pragma unroll
        for (int p = 0; p < 4; ++p)
            gld_lds16(src + p * 256, &sBC[buf][4 * w + p][0][0]);
    };
    const int lp = tid >> 3, lw = (tid >> 1) & 3, lst = tid & 1;
    auto loadDT = [&](int c, float& odt, float& odx) {
        if (tid < 128) {
            size_t g = (rowbase + c * 32 + lp * 2 + lst) * kDINNER + d0 + lw;
            odt = dt[g];
            odx = odt * (float)((const __bf16*)xc)[g];
        }
    };
    auto writeDT = [&](int buf, float vdt, float vdx) {
        if (tid < 128) {
            sDT[buf][lp][lw][lst * 2]     = vdt;
            sDT[buf][lp][lw][lst * 2 + 1] = vdx;
        }
    };
    auto loadEP = [&](int c, float& oxv, float& ozv) {
        size_t g = (rowbase + c * 32 + (lane & 31)) * kDINNER + d;
        oxv = (float)((const __bf16*)xc)[g];
        ozv = (float)((const __bf16*)zs)[g];
    };
    // 16-step recurrence into yv; P0 = first pair index (0 or 8)
    auto recur16 = [&](int buf, int P0, float (&yv)[16]) {
#pragma unroll
        for (int p = 0; p < 8; ++p) {
            float4 bc = *reinterpret_cast<const float4*>(&sBC[buf][P0 + p][lane][0]);
            float4 dd = *reinterpret_cast<const float4*>(&sDT[buf][P0 + p][w][0]);
            float dA0 = exp2f(dd.x * a2);
            s = fmaf(dA0, s, dd.y * bc.x);
            yv[2 * p] = s * bc.y;
            float dA1 = exp2f(dd.z * a2);
            s = fmaf(dA1, s, dd.w * bc.z);
            yv[2 * p + 1] = s * bc.w;
        }
    };
    // 16-wide transpose-reduce: returns, in lane L, the full 64-lane sum of
    // step (L&15) of this half.
    auto tree16 = [&](float (&yv)[16]) -> float {
#pragma unroll
        for (int m = 0; m < 8; ++m) {
            float av = yv[2 * m], bv = yv[2 * m + 1];
            float cv = (lane & 1) ? bv : av;
            float dv = (lane & 1) ? av : bv;
            yv[m] = cv + dpp_mov<0xB1>(dv);     // quad_perm [1,0,3,2]
        }
#pragma unroll
        for (int m = 0; m < 4; ++m) {
            float av = yv[2 * m], bv = yv[2 * m + 1];
            float cv = (lane & 2) ? bv : av;
            float dv = (lane & 2) ? av : bv;
            yv[m] = cv + dpp_mov<0x4E>(dv);     // quad_perm [2,3,0,1]
        }
#pragma unroll
        for (int m = 0; m < 2; ++m) {
            float av = yv[2 * m], bv = yv[2 * m + 1];
            float cv = (lane & 4) ? bv : av;
            float dv = (lane & 4) ? av : bv;
            yv[m] = cv + __shfl_xor(dv, 4, 64);
        }
        {
            float av = yv[0], bv = yv[1];
            float cv = (lane & 8) ? bv : av;
            float dv = (lane & 8) ? av : bv;
            yv[0] = cv + __shfl_xor(dv, 8, 64);
        }
        float y = yv[0];
        y += __shfl_xor(y, 16, 64);
        y += __shfl_xor(y, 32, 64);
        return y;
    };

    float pdt = 0.f, pdx = 0.f, exv = 0.f, ezv = 0.f;
    stageBC(0, 0);
    loadDT(0, pdt, pdx);
    loadEP(0, exv, ezv);
    writeDT(0, pdt, pdx);
    __syncthreads();

    for (int c = 0; c < kT / 32; ++c) {
        const int buf = c & 1;
        float ndt = 0.f, ndx = 0.f, nxv = 0.f, nzv = 0.f;
        const bool more = (c + 1 < kT / 32);
        if (more) {
            stageBC(c + 1, buf ^ 1);
            loadDT(c + 1, ndt, ndx);
            loadEP(c + 1, nxv, nzv);
        }

        __builtin_amdgcn_s_setprio(1);
        float yvA[16], yvB[16];
        recur16(buf, 0, yvA);
        // recurB and treeA are independent -> scheduler overlaps them
        recur16(buf, 8, yvB);
        float yA = tree16(yvA);
        float yB = tree16(yvB);
        __builtin_amdgcn_s_setprio(0);

        // lane L (<32) stores step L: steps 0-15 from yA, 16-31 from yB
        float ysel = (lane & 16) ? yB : yA;
        float yo = fmaf(dsk, exv, ysel) * ezv;
        if (lane < 32) {
            size_t g = (rowbase + c * 32 + lane) * kDINNER + d;
            yg[g] = __float2bfloat16(yo);
        }
        if (more) writeDT(buf ^ 1, ndt, ndx);
        __syncthreads();
        exv = nxv; ezv = nzv;
    }
}

// ---------------------------------------------------------------------------
// Fused tail: LayerNorm(last token) + gelu(ln@W1+b1) @ W2 + b2. 4 blocks.
// ---------------------------------------------------------------------------
__global__ __launch_bounds__(256) void ln_head_kernel(
    const float* __restrict__ h,
    const float* __restrict__ g, const float* __restrict__ be,
    const float* __restrict__ W1, const float* __restrict__ b1,
    const float* __restrict__ W2, const float* __restrict__ b2,
    float* __restrict__ out)
{
    __shared__ float sln[512];
    __shared__ float shid[512];
    __shared__ float sbuf[8];
    const int b = blockIdx.x, tid = threadIdx.x;
    const float* row = h + (size_t)(b * kT + (kT - 1)) * kDMODEL;

    float v0 = row[tid], v1 = row[tid + 256];
    float s = v0 + v1;
    float q = v0 * v0 + v1 * v1;
#pragma unroll
    for (int m = 32; m >= 1; m >>= 1) {
        s += __shfl_xor(s, m, 64);
        q += __shfl_xor(q, m, 64);
    }
    int wid = tid >> 6;
    if ((tid & 63) == 0) { sbuf[wid] = s; sbuf[4 + wid] = q; }
    __syncthreads();
    if (tid == 0) {
        float S = 0.f, Q = 0.f;
        for (int i = 0; i < 4; ++i) { S += sbuf[i]; Q += sbuf[4 + i]; }
        sbuf[0] = S; sbuf[4] = Q;
    }
    __syncthreads();
    float mean = sbuf[0] * (1.f / kDMODEL);
    float var  = sbuf[4] * (1.f / kDMODEL) - mean * mean;
    float inv  = rsqrtf(var + 1e-5f);
    sln[tid]       = (v0 - mean) * inv * g[tid]       + be[tid];
    sln[tid + 256] = (v1 - mean) * inv * g[tid + 256] + be[tid + 256];
    __syncthreads();

    float a0 = b1[tid], a1 = b1[tid + 256];
#pragma unroll 8
    for (int k = 0; k < kDMODEL; ++k) {
        float lv = sln[k];
        a0 = fmaf(lv, W1[(size_t)k * kDMODEL + tid],       a0);
        a1 = fmaf(lv, W1[(size_t)k * kDMODEL + tid + 256], a1);
    }
    shid[tid]       = gelu_f(a0);
    shid[tid + 256] = gelu_f(a1);
    __syncthreads();

    if (tid < kHOR * kDOUT) {
        float acc = b2[tid];
#pragma unroll 8
        for (int k = 0; k < kDMODEL; ++k)
            acc = fmaf(shid[k], W2[(size_t)k * (kHOR * kDOUT) + tid], acc);
        out[b * (kHOR * kDOUT) + tid] = acc;
    }
}

// ---------------------------------------------------------------------------
extern "C" void kernel_launch(void* const* d_in, const int* in_sizes, int n_in,
                              void* d_out, int out_size, void* d_ws, size_t ws_size,
                              hipStream_t stream)
{
    const float* x      = (const float*)d_in[0];
    const float* W_in   = (const float*)d_in[1];
    const float* b_in   = (const float*)d_in[2];
    const float* W_xz   = (const float*)d_in[3];   // (2,512,2048)
    const float* conv_w = (const float*)d_in[4];
    const float* conv_b = (const float*)d_in[5];
    const float* W_xp   = (const float*)d_in[6];   // (2,1024,160)
    const float* W_dt   = (const float*)d_in[7];   // (2,32,1024)
    const float* b_dt   = (const float*)d_in[8];
    const float* A_log  = (const float*)d_in[9];
    const float* D_skip = (const float*)d_in[10];
    const float* W_out  = (const float*)d_in[11];  // (2,1024,512)
    const float* ln_g   = (const float*)d_in[12];
    const float* ln_b   = (const float*)d_in[13];
    const float* W_h1   = (const float*)d_in[14];
    const float* b_h1   = (const float*)d_in[15];
    const float* W_h2   = (const float*)d_in[16];
    const float* b_h2   = (const float*)d_in[17];
    float* out = (float*)d_out;

    // Workspace layout
    char* p = (char*)d_ws;
    auto alloc = [&](size_t bytes) { char* q = p; p += (bytes + 255) & ~(size_t)255; return q; };
    float*          h       = (float*)         alloc((size_t)kBT * kDMODEL * 4);
    __hip_bfloat16* h_bf    = (__hip_bfloat16*)alloc((size_t)kBT * kDMODEL * 2);
    __hip_bfloat16* xb_bf   = (__hip_bfloat16*)alloc((size_t)kBT * kDINNER * 2);
    __hip_bfloat16* z_bf    = (__hip_bfloat16*)alloc((size_t)kBT * kDINNER * 2);
    __hip_bfloat16* xc_bf   = (__hip_bfloat16*)alloc((size_t)kBT * kDINNER * 2);
    float*          xdbi    = (float*)         alloc((size_t)(kBT / 2) * 256 * 4);   // 2 MB
    __hip_bfloat16* xdb_bf  = (__hip_bfloat16*)alloc((size_t)kBT * kXPAD * 2);
    float*          dtb     = (float*)         alloc((size_t)kBT * kDINNER * 4);     // 16 MB
    __hip_bfloat16* ys_bf   = (__hip_bfloat16*)alloc((size_t)kBT * kDINNER * 2);
    __hip_bfloat16* wxz_bt  = (__hip_bfloat16*)alloc((size_t)2 * 2048 * 512 * 2);
    __hip_bfloat16* wxp_bt  = (__hip_bfloat16*)alloc((size_t)2 * 256 * 1024 * 2);
    __hip_bfloat16* wdt_bt  = (__hip_bfloat16*)alloc((size_t)2 * 1024 * 64 * 2);
    __hip_bfloat16* wout_bt = (__hip_bfloat16*)alloc((size_t)2 * 512 * 1024 * 2);
    float*          wfold   = (float*)         alloc((size_t)2048 * 12 * 4);

    // One-time prep: weight transposes + layer-0 folded weight
    wtrans_all_kernel<<<3520, 256, 0, stream>>>(
        W_xz, W_xp, W_dt, W_out, wxz_bt, wxp_bt, wdt_bt, wout_bt);
    wfold_kernel<<<32, 256, 0, stream>>>(W_in, b_in, W_xz, wfold);

    for (int l = 0; l < kNLAYER; ++l) {
        const float* cw_l  = conv_w + (size_t)l * kDINNER * 4;
        const float* cb_l  = conv_b + (size_t)l * kDINNER;
        const float* bdt_l = b_dt   + (size_t)l * kDINNER;
        const float* Al_l  = A_log  + (size_t)l * kDINNER * kDSTATE;
        const float* Dsk_l = D_skip + (size_t)l * kDINNER;
        const __hip_bfloat16* wxz_l  = wxz_bt  + (size_t)l * 2048 * 512;
        const __hip_bfloat16* wxp_l  = wxp_bt  + (size_t)l * 256 * 1024;
        const __hip_bfloat16* wdt_l  = wdt_bt  + (size_t)l * 1024 * 64;
        const __hip_bfloat16* wout_l = wout_bt + (size_t)l * 512 * 1024;

        if (l == 0) {
            // fused xz + conv + silu for layer 0 (K=8 folded weight)
            xz0_conv_kernel<<<kBT * 2, 256, 0, stream>>>(
                x, wfold, cw_l, cb_l, xc_bf, z_bf);
        } else {
            mfma_gemm_bt<4, 128, 64><<<dim3(32, 32), 256, 0, stream>>>(
                h_bf, kDMODEL, wxz_l, 512, nullptr, (float*)xb_bf, kDINNER, z_bf, kDMODEL);
            conv_silu_kernel<<<(kBT * 128) / 256, 256, 0, stream>>>(xb_bf, cw_l, cb_l, xc_bf);
        }
        // xdb = xc @ W_xproj : dt-rank -> xdb_bf ; B,C -> pair-interleaved xdbi
        mfma_gemm_bt<5, 64, 64><<<dim3(3, 64), 256, 0, stream>>>(
            xc_bf, kDINNER, wxp_l, 1024, nullptr, xdbi, 0, xdb_bf, kDINNER);
        // dt = softplus(xdb[:,:32] @ W_dt + b_dt) -> plain coalesced f32
        mfma_gemm_bt<2, 64, 64><<<dim3(16, 64), 256, 0, stream>>>(
            xdb_bf, kXPAD, wdt_l, 64, bdt_l, dtb, kDINNER, nullptr, 64);
        // scan + gate -> ys (bf16)
        scan_kernel<<<kB * kDINNER / 4, 256, 0, stream>>>(
            dtb, xdbi, xc_bf, z_bf, Al_l, Dsk_l, ys_bf);
        // h = ys @ W_out: layer 0 -> bf16 only (f32 h never read);
        //                 layer 1 -> f32 only (bf16 never read)
        if (l == 0) {
            mfma_gemm_bt<6, 64, 64><<<dim3(8, 64), 256, 0, stream>>>(
                ys_bf, kDINNER, wout_l, 1024, nullptr, nullptr, kDMODEL, h_bf, kDINNER);
        } else {
            mfma_gemm_bt<0, 64, 64><<<dim3(8, 64), 256, 0, stream>>>(
                ys_bf, kDINNER, wout_l, 1024, nullptr, h, kDMODEL, nullptr, kDINNER);
        }
    }

    // Fused tail: LN + 2-layer head
    ln_head_kernel<<<kB, 256, 0, stream>>>(h, ln_g, ln_b, W_h1, b_h1, W_h2, b_h2, out);
}

// Round 14
// 474.764 us; speedup vs baseline: 1.0094x; 1.0094x over previous
//
#include <hip/hip_runtime.h>
#include <hip/hip_bf16.h>

// Problem constants
static constexpr int kB      = 4;
static constexpr int kT      = 1024;
static constexpr int kDIN    = 8;
static constexpr int kDMODEL = 512;
static constexpr int kHOR    = 24;
static constexpr int kDOUT   = 8;
static constexpr int kDSTATE = 64;
static constexpr int kDINNER = 1024;
static constexpr int kDTRANK = 32;
static constexpr int kXPROJ  = 160;          // 32 + 64 + 64
static constexpr int kXPAD   = 256;          // padded xdb_bf row stride
static constexpr int kBT     = kB * kT;      // 4096
static constexpr int kNLAYER = 2;

typedef __bf16 bf16x8 __attribute__((ext_vector_type(8)));
typedef float  f32x4  __attribute__((ext_vector_type(4)));

__device__ __forceinline__ float silu_f(float x)     { return x / (1.f + __expf(-x)); }
__device__ __forceinline__ float softplus_f(float x) { return (x > 20.f) ? x : log1pf(__expf(x)); }
__device__ __forceinline__ float gelu_f(float x)     { return 0.5f * x * (1.f + erff(x * 0.70710678118654752f)); }

// async global->LDS 16B
__device__ __forceinline__ void gld_lds16(const void* g, void* l) {
    __builtin_amdgcn_global_load_lds(
        (const __attribute__((address_space(1))) unsigned int*)g,
        (__attribute__((address_space(3))) unsigned int*)l, 16, 0, 0);
}

template<int CTRL>
__device__ __forceinline__ float dpp_mov(float v) {
    return __int_as_float(__builtin_amdgcn_update_dpp(
        0, __float_as_int(v), CTRL, 0xf, 0xf, false));
}

// ---------------------------------------------------------------------------
// ALL weight prep in ONE dispatch (region-decoded flat grid).
// Regions: xz [0,2048)  xp [2048,2368)  dt [2368,2496)  wout [2496,3520)
//          wfold [3520,3552)
// Transpose: out[n][k] = bf16(in[k][n]); OOB reads -> 0.
// wfold: wf[n][0..7] = (W_in @ W_xz0)^T per col; wf[n][8] = b_in @ W_xz0.
// ---------------------------------------------------------------------------
__global__ __launch_bounds__(256) void wprep_all_kernel(
    const float* __restrict__ Wxz, const float* __restrict__ Wxp,
    const float* __restrict__ Wdt, const float* __restrict__ Wout,
    const float* __restrict__ Win, const float* __restrict__ bin,
    __hip_bfloat16* __restrict__ oxz, __hip_bfloat16* __restrict__ oxp,
    __hip_bfloat16* __restrict__ odt, __hip_bfloat16* __restrict__ oout,
    float* __restrict__ wf)
{
    __shared__ float tile[32][33];
    __shared__ float sred[3][64][9];
    const int bid = blockIdx.x;
    const int tid = threadIdx.x;

    if (bid >= 3520) {   // ---- wfold region ----
        const int t    = tid & 63;
        const int part = tid >> 6;
        const int col  = (bid - 3520) * 64 + t;

        float acc[9];
#pragma unroll
        for (int r = 0; r < 9; ++r) acc[r] = 0.f;
        const int k0 = part * 128;
#pragma unroll 4
        for (int k = k0; k < k0 + 128; ++k) {
            float wv = Wxz[(size_t)k * 2048 + col];
#pragma unroll
            for (int r = 0; r < 8; ++r)
                acc[r] = fmaf(Win[r * kDMODEL + k], wv, acc[r]);
            acc[8] = fmaf(bin[k], wv, acc[8]);
        }
        if (part > 0) {
#pragma unroll
            for (int r = 0; r < 9; ++r) sred[part - 1][t][r] = acc[r];
        }
        __syncthreads();
        if (part == 0) {
#pragma unroll
            for (int r = 0; r < 9; ++r)
                wf[(size_t)col * 12 + r] =
                    acc[r] + sred[0][t][r] + sred[1][t][r] + sred[2][t][r];
        }
        return;
    }

    // ---- transpose regions ----
    const float* in; __hip_bfloat16* out;
    int K, N, Kpad, TX, loc;
    if (bid < 2048) {               // W_xz: (512,2048) -> (2048,512), 64x16 tiles
        int l = bid >> 10; loc = bid & 1023;
        in = Wxz + (size_t)l * 512 * 2048; out = oxz + (size_t)l * 2048 * 512;
        K = 512; N = 2048; Kpad = 512; TX = 64;
    } else if (bid < 2368) {        // W_xp: (1024,160) -> (256pad,1024), 5x32 tiles
        int r = bid - 2048; int l = r / 160; loc = r % 160;
        in = Wxp + (size_t)l * 1024 * 160; out = oxp + (size_t)l * 256 * 1024;
        K = 1024; N = 160; Kpad = 1024; TX = 5;
    } else if (bid < 2496) {        // W_dt: (32,1024) -> (1024,64pad), 32x2 tiles
        int r = bid - 2368; int l = r >> 6; loc = r & 63;
        in = Wdt + (size_t)l * 32 * 1024; out = odt + (size_t)l * 1024 * 64;
        K = 32; N = 1024; Kpad = 64; TX = 32;
    } else {                        // W_out: (1024,512) -> (512,1024), 16x32 tiles
        int r = bid - 2496; int l = r >> 9; loc = r & 511;
        in = Wout + (size_t)l * 1024 * 512; out = oout + (size_t)l * 512 * 1024;
        K = 1024; N = 512; Kpad = 1024; TX = 16;
    }
    const int n0 = (loc % TX) * 32;
    const int k0 = (loc / TX) * 32;

#pragma unroll
    for (int p = 0; p < 4; ++p) {
        int idx = p * 256 + tid;
        int ki = idx >> 5, ni = idx & 31;
        float v = 0.f;
        if (k0 + ki < K && n0 + ni < N) v = in[(size_t)(k0 + ki) * N + n0 + ni];
        tile[ki][ni] = v;
    }
    __syncthreads();
#pragma unroll
    for (int p = 0; p < 4; ++p) {
        int idx = p * 256 + tid;
        int ni = idx >> 5, ki = idx & 31;
        if (n0 + ni < N)
            out[(size_t)(n0 + ni) * Kpad + k0 + ki] = __float2bfloat16(tile[ki][ni]);
    }
}

// ---------------------------------------------------------------------------
// Layer-0 fused xz + conv + SiLU (K=8 folded weight).
// blockIdx = m*2 + half. half 0: xc = silu(conv(xb taps computed on the fly));
// half 1: z = silu(dot). 4 cols/thread.
// ---------------------------------------------------------------------------
__global__ __launch_bounds__(256) void xz0_conv_kernel(
    const float* __restrict__ x, const float* __restrict__ wf,
    const float* __restrict__ cw, const float* __restrict__ cb,
    __hip_bfloat16* __restrict__ xcv, __hip_bfloat16* __restrict__ z)
{
    const int bid  = blockIdx.x;
    const int m    = bid >> 1;
    const int half = bid & 1;
    const int t    = m & (kT - 1);
    const int n4   = threadIdx.x * 4 + half * kDINNER;

    float wreg[4][9];
#pragma unroll
    for (int c = 0; c < 4; ++c) {
        const float* wc = wf + (size_t)(n4 + c) * 12;
#pragma unroll
        for (int r = 0; r < 9; ++r) wreg[c][r] = wc[r];
    }

    if (half == 1) {
        const float* xr = x + (size_t)m * kDIN;
        float xv[8];
#pragma unroll
        for (int r = 0; r < 8; ++r) xv[r] = xr[r];
        __bf16 o4[4];
#pragma unroll
        for (int c = 0; c < 4; ++c) {
            float a = wreg[c][8];
#pragma unroll
            for (int r = 0; r < 8; ++r) a = fmaf(xv[r], wreg[c][r], a);
            o4[c] = (__bf16)silu_f(a);
        }
        *reinterpret_cast<ushort4*>(z + (size_t)m * kDINNER + (n4 - kDINNER)) =
            *reinterpret_cast<ushort4*>(o4);
    } else {
        float acc[4];
        float4 cwv[4];
#pragma unroll
        for (int c = 0; c < 4; ++c) {
            acc[c] = cb[n4 + c];
            cwv[c] = *reinterpret_cast<const float4*>(cw + (n4 + c) * 4);
        }
#pragma unroll
        for (int sh = 0; sh < 4; ++sh) {
            if (t >= sh) {
                const float* xr = x + (size_t)(m - sh) * kDIN;
                float xv[8];
#pragma unroll
                for (int r = 0; r < 8; ++r) xv[r] = xr[r];
#pragma unroll
                for (int c = 0; c < 4; ++c) {
                    float a = wreg[c][8];
#pragma unroll
                    for (int r = 0; r < 8; ++r) a = fmaf(xv[r], wreg[c][r], a);
                    float wk = (sh == 0) ? cwv[c].w : (sh == 1) ? cwv[c].z
                             : (sh == 2) ? cwv[c].y : cwv[c].x;
                    acc[c] = fmaf(a, wk, acc[c]);
                }
            }
        }
        __bf16 o4[4];
#pragma unroll
        for (int c = 0; c < 4; ++c) o4[c] = (__bf16)silu_f(acc[c]);
        *reinterpret_cast<ushort4*>(xcv + (size_t)m * kDINNER + n4) =
            *reinterpret_cast<ushort4*>(o4);
    }
}

// ---------------------------------------------------------------------------
// MFMA bf16 GEMM, B-transposed. BM in {128,64}, BN in {128,64}, BK=64, 4 waves.
// MODE 0: f32 C only
// MODE 2: dt: softplus(v + bias[col]) -> f32 C (coalesced)
// MODE 4: XZ split, both bf16 (col<1024 -> bf16 xb ; col>=1024 -> silu -> z)
// MODE 5: xproj split: col<32 -> bf16 C2 (stride kXPAD);
//         col 32..96  -> B: C[(row>>1)*256 + (col-32)*4 + (row&1)*2]
//         col 96..160 -> C: C[(row>>1)*256 + (col-96)*4 + (row&1)*2 + 1]
// MODE 6: bf16 C2 only (stride ldc)
// ---------------------------------------------------------------------------
template<int MODE, int BM, int BN>
__global__ __launch_bounds__(256) void mfma_gemm_bt(
    const __hip_bfloat16* __restrict__ A, int lda,
    const __hip_bfloat16* __restrict__ BT, int ldb,
    const float* __restrict__ bias,
    float* __restrict__ C, int ldc,
    void* __restrict__ C2,
    int K)
{
    constexpr int WN  = (BM == 128 && BN == 64) ? 1 : 2;
    constexpr int WM  = 4 / WN;
    constexpr int WTM = BM / WM;
    constexpr int WTN = BN / WN;
    constexpr int MI  = WTM / 16;
    constexpr int NJ  = WTN / 16;

    __shared__ __align__(16) __hip_bfloat16 sA[BM][64];
    __shared__ __align__(16) __hip_bfloat16 sB[BN][64];

    const int tid  = threadIdx.x;
    const int lane = tid & 63;
    const int w    = tid >> 6;
    const int m0   = blockIdx.y * BM;
    const int n0   = blockIdx.x * BN;
    const int wm   = (WN == 1) ? w : (w >> 1);
    const int wn   = (WN == 1) ? 0 : (w & 1);

    f32x4 acc[MI][NJ] = {};

    const int lrow = lane & 15;
    const int lk   = (lane >> 4) << 3;

    const int grow = tid >> 3;
    const int gcol = (tid & 7) * 8;
    char* ldsA = (char*)&sA[0][0] + w * 1024;
    char* ldsB = (char*)&sB[0][0] + w * 1024;

    for (int k0 = 0; k0 < K; k0 += 64) {
        __syncthreads();
#pragma unroll
        for (int p = 0; p < BM / 32; ++p)
            gld_lds16(A + (size_t)(m0 + grow + p * 32) * lda + k0 + gcol, ldsA + p * 4096);
#pragma unroll
        for (int p = 0; p < BN / 32; ++p)
            gld_lds16(BT + (size_t)(n0 + grow + p * 32) * ldb + k0 + gcol, ldsB + p * 4096);
        __syncthreads();
#pragma unroll
        for (int ks = 0; ks < 2; ++ks) {
            bf16x8 af[MI], bfr[NJ];
#pragma unroll
            for (int i = 0; i < MI; ++i)
                af[i] = *reinterpret_cast<const bf16x8*>(&sA[wm * WTM + i * 16 + lrow][ks * 32 + lk]);
#pragma unroll
            for (int j = 0; j < NJ; ++j)
                bfr[j] = *reinterpret_cast<const bf16x8*>(&sB[wn * WTN + j * 16 + lrow][ks * 32 + lk]);
#pragma unroll
            for (int i = 0; i < MI; ++i)
#pragma unroll
                for (int j = 0; j < NJ; ++j)
                    acc[i][j] = __builtin_amdgcn_mfma_f32_16x16x32_bf16(af[i], bfr[j], acc[i][j], 0, 0, 0);
        }
    }

    const int crow = (lane >> 4) * 4;
    const int ccol = lane & 15;
#pragma unroll
    for (int i = 0; i < MI; ++i) {
#pragma unroll
        for (int j = 0; j < NJ; ++j) {
#pragma unroll
            for (int r = 0; r < 4; ++r) {
                int row = m0 + wm * WTM + i * 16 + crow + r;
                int col = n0 + wn * WTN + j * 16 + ccol;
                float v = acc[i][j][r];
                if (MODE == 0) {
                    C[(size_t)row * ldc + col] = v;
                } else if (MODE == 2) {
                    C[(size_t)row * ldc + col] = softplus_f(v + bias[col]);
                } else if (MODE == 4) {
                    if (col < kDINNER)
                        ((__hip_bfloat16*)C)[(size_t)row * ldc + col] = __float2bfloat16(v);
                    else
                        ((__hip_bfloat16*)C2)[(size_t)row * ldc + (col - kDINNER)] =
                            __float2bfloat16(silu_f(v));
                } else if (MODE == 5) {
                    if (col < kDTRANK)
                        ((__hip_bfloat16*)C2)[(size_t)row * kXPAD + col] = __float2bfloat16(v);
                    else if (col < kDTRANK + kDSTATE)
                        C[(size_t)(row >> 1) * 256 + (col - kDTRANK) * 4 + (row & 1) * 2] = v;
                    else if (col < kXPROJ)
                        C[(size_t)(row >> 1) * 256 + (col - kDTRANK - kDSTATE) * 4 + (row & 1) * 2 + 1] = v;
                } else {  // MODE 6: bf16 only
                    ((__hip_bfloat16*)C2)[(size_t)row * ldc + col] = __float2bfloat16(v);
                }
            }
        }
    }
}

// ---------------------------------------------------------------------------
// Depthwise causal conv (width 4) + bias + SiLU. 8 channels/thread. (layer 1)
// ---------------------------------------------------------------------------
__global__ __launch_bounds__(256) void conv_silu_kernel(
    const __hip_bfloat16* __restrict__ xb,
    const float* __restrict__ cw, const float* __restrict__ cb,
    __hip_bfloat16* __restrict__ xc)
{
    int idx = blockIdx.x * 256 + threadIdx.x;      // over BT*128
    int dg  = (idx & 127) * 8;
    int bt  = idx >> 7;
    int t   = bt & (kT - 1);

    float4 wv[8];
#pragma unroll
    for (int k = 0; k < 8; ++k)
        wv[k] = *reinterpret_cast<const float4*>(cw + (dg + k) * 4);

    float acc[8];
#pragma unroll
    for (int k = 0; k < 8; ++k) acc[k] = cb[dg + k];

    const __hip_bfloat16* base = xb + (size_t)bt * kDINNER + dg;
    {
        bf16x8 v = *reinterpret_cast<const bf16x8*>(base);
#pragma unroll
        for (int k = 0; k < 8; ++k) acc[k] = fmaf((float)v[k], wv[k].w, acc[k]);
    }
    if (t >= 1) {
        bf16x8 v = *reinterpret_cast<const bf16x8*>(base - kDINNER);
#pragma unroll
        for (int k = 0; k < 8; ++k) acc[k] = fmaf((float)v[k], wv[k].z, acc[k]);
    }
    if (t >= 2) {
        bf16x8 v = *reinterpret_cast<const bf16x8*>(base - 2 * kDINNER);
#pragma unroll
        for (int k = 0; k < 8; ++k) acc[k] = fmaf((float)v[k], wv[k].y, acc[k]);
    }
    if (t >= 3) {
        bf16x8 v = *reinterpret_cast<const bf16x8*>(base - 3 * kDINNER);
#pragma unroll
        for (int k = 0; k < 8; ++k) acc[k] = fmaf((float)v[k], wv[k].x, acc[k]);
    }
    bf16x8 o;
#pragma unroll
    for (int k = 0; k < 8; ++k) o[k] = (__bf16)silu_f(acc[k]);
    *reinterpret_cast<bf16x8*>(xc + (size_t)bt * kDINNER + dg) = o;
}

// ---------------------------------------------------------------------------
// Selective scan (proven version: ~123.4us, VALUBusy 87%, no spill).
// Block = 4 waves (channels d0..d0+3, same b); lane = state n.
// XCD remap: batch b owns an XCD pair -> its panels stay L2-resident.
// BC: pair-interleaved (B0,C0,B1,C1), staged via global_load_lds, one
// ds_read_b128 per lane per 2 steps. DT: (dt,dtx) pairs built in registers
// from coalesced dt[bt][1024] + xc, written to LDS once per chunk.
// Select+shuffle transpose-reduce.
// ---------------------------------------------------------------------------
__global__ __launch_bounds__(256, 4) void scan_kernel(
    const float* __restrict__ dt,            // (bt,1024) f32
    const float* __restrict__ xdbi,          // (bt/2, 64, 4): B0,C0,B1,C1
    const __hip_bfloat16* __restrict__ xc,   // (bt,1024)
    const __hip_bfloat16* __restrict__ zs,   // (bt,1024) silu(z)
    const float* __restrict__ Alog,          // (1024,64)
    const float* __restrict__ Dsk,           // (1024,)
    __hip_bfloat16* __restrict__ yg)         // (bt,1024)
{
    __shared__ __align__(16) float sBC[2][16][64][4];  // 32 KB
    __shared__ __align__(16) float sDT[2][16][4][4];   // 2 KB

    const int tid  = threadIdx.x;
    const int lane = tid & 63;
    const int w    = tid >> 6;
    const int bb = blockIdx.x;
    const int b  = (bb & 7) >> 1;
    const int d0 = ((bb >> 3) + (bb & 1) * 128) * 4;
    const int d  = d0 + w;

    const float a2  = -__expf(Alog[d * kDSTATE + lane]) * 1.44269504f;
    const float dsk = Dsk[d];
    const size_t rowbase  = (size_t)b * kT;
    const size_t pairbase = (size_t)b * (kT / 2);
    float s = 0.f;

    auto stageBC = [&](int c, int buf) {
        const float* src = xdbi + (pairbase + c * 16 + 4 * w) * 256 + lane * 4;
#pragma unroll
        for (int p = 0; p < 4; ++p)
            gld_lds16(src + p * 256, &sBC[buf][4 * w + p][0][0]);
    };
    const int lp = tid >> 3, lw = (tid >> 1) & 3, lst = tid & 1;
    auto loadDT = [&](int c, float& odt, float& odx) {
        if (tid < 128) {
            size_t g = (rowbase + c * 32 + lp * 2 + lst) * kDINNER + d0 + lw;
            odt = dt[g];
            odx = odt * (float)((const __bf16*)xc)[g];
        }
    };
    auto writeDT = [&](int buf, float vdt, float vdx) {
        if (tid < 128) {
            sDT[buf][lp][lw][lst * 2]     = vdt;
            sDT[buf][lp][lw][lst * 2 + 1] = vdx;
        }
    };
    auto loadEP = [&](int c, float& oxv, float& ozv) {
        size_t g = (rowbase + c * 32 + (lane & 31)) * kDINNER + d;
        oxv = (float)((const __bf16*)xc)[g];
        ozv = (float)((const __bf16*)zs)[g];
    };

    float pdt = 0.f, pdx = 0.f, exv = 0.f, ezv = 0.f;
    stageBC(0, 0);
    loadDT(0, pdt, pdx);
    loadEP(0, exv, ezv);
    writeDT(0, pdt, pdx);
    __syncthreads();

    for (int c = 0; c < kT / 32; ++c) {
        const int buf = c & 1;
        float ndt = 0.f, ndx = 0.f, nxv = 0.f, nzv = 0.f;
        const bool more = (c + 1 < kT / 32);
        if (more) {
            stageBC(c + 1, buf ^ 1);
            loadDT(c + 1, ndt, ndx);
            loadEP(c + 1, nxv, nzv);
        }

        __builtin_amdgcn_s_setprio(1);
        float yv[32];
#pragma unroll
        for (int p = 0; p < 16; ++p) {
            float4 bc = *reinterpret_cast<const float4*>(&sBC[buf][p][lane][0]);
            float4 dd = *reinterpret_cast<const float4*>(&sDT[buf][p][w][0]);
            float dA0 = exp2f(dd.x * a2);
            s = fmaf(dA0, s, dd.y * bc.x);
            yv[2 * p] = s * bc.y;
            float dA1 = exp2f(dd.z * a2);
            s = fmaf(dA1, s, dd.w * bc.z);
            yv[2 * p + 1] = s * bc.w;
        }

        // transpose-reduce: lane L -> full 64-lane sum of step (L&31)
#pragma unroll
        for (int m = 0; m < 16; ++m) {
            float av = yv[2 * m], bv = yv[2 * m + 1];
            float cv = (lane & 1) ? bv : av;
            float dv = (lane & 1) ? av : bv;
            yv[m] = cv + dpp_mov<0xB1>(dv);     // quad_perm [1,0,3,2]
        }
#pragma unroll
        for (int m = 0; m < 8; ++m) {
            float av = yv[2 * m], bv = yv[2 * m + 1];
            float cv = (lane & 2) ? bv : av;
            float dv = (lane & 2) ? av : bv;
            yv[m] = cv + dpp_mov<0x4E>(dv);     // quad_perm [2,3,0,1]
        }
#pragma unroll
        for (int j = 2; j < 5; ++j) {
            const int S = 1 << j;
#pragma unroll
            for (int m = 0; m < (32 >> (j + 1)); ++m) {
                float av = yv[2 * m], bv = yv[2 * m + 1];
                float cv = (lane & S) ? bv : av;
                float dv = (lane & S) ? av : bv;
                yv[m] = cv + __shfl_xor(dv, S, 64);
            }
        }
        float y = yv[0];
        y += __shfl_xor(y, 32, 64);
        __builtin_amdgcn_s_setprio(0);

        float yo = fmaf(dsk, exv, y) * ezv;
        if (lane < 32) {
            size_t g = (rowbase + c * 32 + lane) * kDINNER + d;
            yg[g] = __float2bfloat16(yo);
        }
        if (more) writeDT(buf ^ 1, ndt, ndx);
        __syncthreads();
        exv = nxv; ezv = nzv;
    }
}

// ---------------------------------------------------------------------------
// Fused tail: LayerNorm(last token) + gelu(ln@W1+b1) @ W2 + b2. 4 blocks.
// ---------------------------------------------------------------------------
__global__ __launch_bounds__(256) void ln_head_kernel(
    const float* __restrict__ h,
    const float* __restrict__ g, const float* __restrict__ be,
    const float* __restrict__ W1, const float* __restrict__ b1,
    const float* __restrict__ W2, const float* __restrict__ b2,
    float* __restrict__ out)
{
    __shared__ float sln[512];
    __shared__ float shid[512];
    __shared__ float sbuf[8];
    const int b = blockIdx.x, tid = threadIdx.x;
    const float* row = h + (size_t)(b * kT + (kT - 1)) * kDMODEL;

    float v0 = row[tid], v1 = row[tid + 256];
    float s = v0 + v1;
    float q = v0 * v0 + v1 * v1;
#pragma unroll
    for (int m = 32; m >= 1; m >>= 1) {
        s += __shfl_xor(s, m, 64);
        q += __shfl_xor(q, m, 64);
    }
    int wid = tid >> 6;
    if ((tid & 63) == 0) { sbuf[wid] = s; sbuf[4 + wid] = q; }
    __syncthreads();
    if (tid == 0) {
        float S = 0.f, Q = 0.f;
        for (int i = 0; i < 4; ++i) { S += sbuf[i]; Q += sbuf[4 + i]; }
        sbuf[0] = S; sbuf[4] = Q;
    }
    __syncthreads();
    float mean = sbuf[0] * (1.f / kDMODEL);
    float var  = sbuf[4] * (1.f / kDMODEL) - mean * mean;
    float inv  = rsqrtf(var + 1e-5f);
    sln[tid]       = (v0 - mean) * inv * g[tid]       + be[tid];
    sln[tid + 256] = (v1 - mean) * inv * g[tid + 256] + be[tid + 256];
    __syncthreads();

    float a0 = b1[tid], a1 = b1[tid + 256];
#pragma unroll 8
    for (int k = 0; k < kDMODEL; ++k) {
        float lv = sln[k];
        a0 = fmaf(lv, W1[(size_t)k * kDMODEL + tid],       a0);
        a1 = fmaf(lv, W1[(size_t)k * kDMODEL + tid + 256], a1);
    }
    shid[tid]       = gelu_f(a0);
    shid[tid + 256] = gelu_f(a1);
    __syncthreads();

    if (tid < kHOR * kDOUT) {
        float acc = b2[tid];
#pragma unroll 8
        for (int k = 0; k < kDMODEL; ++k)
            acc = fmaf(shid[k], W2[(size_t)k * (kHOR * kDOUT) + tid], acc);
        out[b * (kHOR * kDOUT) + tid] = acc;
    }
}

// ---------------------------------------------------------------------------
extern "C" void kernel_launch(void* const* d_in, const int* in_sizes, int n_in,
                              void* d_out, int out_size, void* d_ws, size_t ws_size,
                              hipStream_t stream)
{
    const float* x      = (const float*)d_in[0];
    const float* W_in   = (const float*)d_in[1];
    const float* b_in   = (const float*)d_in[2];
    const float* W_xz   = (const float*)d_in[3];   // (2,512,2048)
    const float* conv_w = (const float*)d_in[4];
    const float* conv_b = (const float*)d_in[5];
    const float* W_xp   = (const float*)d_in[6];   // (2,1024,160)
    const float* W_dt   = (const float*)d_in[7];   // (2,32,1024)
    const float* b_dt   = (const float*)d_in[8];
    const float* A_log  = (const float*)d_in[9];
    const float* D_skip = (const float*)d_in[10];
    const float* W_out  = (const float*)d_in[11];  // (2,1024,512)
    const float* ln_g   = (const float*)d_in[12];
    const float* ln_b   = (const float*)d_in[13];
    const float* W_h1   = (const float*)d_in[14];
    const float* b_h1   = (const float*)d_in[15];
    const float* W_h2   = (const float*)d_in[16];
    const float* b_h2   = (const float*)d_in[17];
    float* out = (float*)d_out;

    // Workspace layout
    char* p = (char*)d_ws;
    auto alloc = [&](size_t bytes) { char* q = p; p += (bytes + 255) & ~(size_t)255; return q; };
    float*          h       = (float*)         alloc((size_t)kBT * kDMODEL * 4);
    __hip_bfloat16* h_bf    = (__hip_bfloat16*)alloc((size_t)kBT * kDMODEL * 2);
    __hip_bfloat16* xb_bf   = (__hip_bfloat16*)alloc((size_t)kBT * kDINNER * 2);
    __hip_bfloat16* z_bf    = (__hip_bfloat16*)alloc((size_t)kBT * kDINNER * 2);
    __hip_bfloat16* xc_bf   = (__hip_bfloat16*)alloc((size_t)kBT * kDINNER * 2);
    float*          xdbi    = (float*)         alloc((size_t)(kBT / 2) * 256 * 4);   // 2 MB
    __hip_bfloat16* xdb_bf  = (__hip_bfloat16*)alloc((size_t)kBT * kXPAD * 2);
    float*          dtb     = (float*)         alloc((size_t)kBT * kDINNER * 4);     // 16 MB
    __hip_bfloat16* ys_bf   = (__hip_bfloat16*)alloc((size_t)kBT * kDINNER * 2);
    __hip_bfloat16* wxz_bt  = (__hip_bfloat16*)alloc((size_t)2 * 2048 * 512 * 2);
    __hip_bfloat16* wxp_bt  = (__hip_bfloat16*)alloc((size_t)2 * 256 * 1024 * 2);
    __hip_bfloat16* wdt_bt  = (__hip_bfloat16*)alloc((size_t)2 * 1024 * 64 * 2);
    __hip_bfloat16* wout_bt = (__hip_bfloat16*)alloc((size_t)2 * 512 * 1024 * 2);
    float*          wfold   = (float*)         alloc((size_t)2048 * 12 * 4);

    // One-time prep: weight transposes + layer-0 folded weight (one dispatch)
    wprep_all_kernel<<<3552, 256, 0, stream>>>(
        W_xz, W_xp, W_dt, W_out, W_in, b_in,
        wxz_bt, wxp_bt, wdt_bt, wout_bt, wfold);

    for (int l = 0; l < kNLAYER; ++l) {
        const float* cw_l  = conv_w + (size_t)l * kDINNER * 4;
        const float* cb_l  = conv_b + (size_t)l * kDINNER;
        const float* bdt_l = b_dt   + (size_t)l * kDINNER;
        const float* Al_l  = A_log  + (size_t)l * kDINNER * kDSTATE;
        const float* Dsk_l = D_skip + (size_t)l * kDINNER;
        const __hip_bfloat16* wxz_l  = wxz_bt  + (size_t)l * 2048 * 512;
        const __hip_bfloat16* wxp_l  = wxp_bt  + (size_t)l * 256 * 1024;
        const __hip_bfloat16* wdt_l  = wdt_bt  + (size_t)l * 1024 * 64;
        const __hip_bfloat16* wout_l = wout_bt + (size_t)l * 512 * 1024;

        if (l == 0) {
            // fused xz + conv + silu for layer 0 (K=8 folded weight)
            xz0_conv_kernel<<<kBT * 2, 256, 0, stream>>>(
                x, wfold, cw_l, cb_l, xc_bf, z_bf);
        } else {
            mfma_gemm_bt<4, 128, 64><<<dim3(32, 32), 256, 0, stream>>>(
                h_bf, kDMODEL, wxz_l, 512, nullptr, (float*)xb_bf, kDINNER, z_bf, kDMODEL);
            conv_silu_kernel<<<(kBT * 128) / 256, 256, 0, stream>>>(xb_bf, cw_l, cb_l, xc_bf);
        }
        // xdb = xc @ W_xproj : dt-rank -> xdb_bf ; B,C -> pair-interleaved xdbi
        mfma_gemm_bt<5, 64, 64><<<dim3(3, 64), 256, 0, stream>>>(
            xc_bf, kDINNER, wxp_l, 1024, nullptr, xdbi, 0, xdb_bf, kDINNER);
        // dt = softplus(xdb[:,:32] @ W_dt + b_dt) -> plain coalesced f32
        mfma_gemm_bt<2, 64, 64><<<dim3(16, 64), 256, 0, stream>>>(
            xdb_bf, kXPAD, wdt_l, 64, bdt_l, dtb, kDINNER, nullptr, 64);
        // scan + gate -> ys (bf16)
        scan_kernel<<<kB * kDINNER / 4, 256, 0, stream>>>(
            dtb, xdbi, xc_bf, z_bf, Al_l, Dsk_l, ys_bf);
        // h = ys @ W_out: layer 0 -> bf16 only; layer 1 -> f32 only
        if (l == 0) {
            mfma_gemm_bt<6, 64, 64><<<dim3(8, 64), 256, 0, stream>>>(
                ys_bf, kDINNER, wout_l, 1024, nullptr, nullptr, kDMODEL, h_bf, kDINNER);
        } else {
            mfma_gemm_bt<0, 64, 64><<<dim3(8, 64), 256, 0, stream>>>(
                ys_bf, kDINNER, wout_l, 1024, nullptr, h, kDMODEL, nullptr, kDINNER);
        }
    }

    // Fused tail: LN + 2-layer head
    ln_head_kernel<<<kB, 256, 0, stream>>>(h, ln_g, ln_b, W_h1, b_h1, W_h2, b_h2, out);
}